// Round 1
// baseline (740.199 us; speedup 1.0000x reference)
//
#include <hip/hip_runtime.h>
#include <hip/hip_bf16.h>
#include <cstdint>

// Problem constants (LongformerSelfAttention: B=2, S=2048, M=768, H=12, D=64, W=256, DIL=1)
#define SEQ    2048
#define HIDDEN 768
#define NHEAD  12
#define HDIM   64
#define WIN    256
#define BATCH  2
#define MTOT   (BATCH * SEQ)   // 4096 tokens

// ---------------------------------------------------------------------------
// Projection GEMM: Y = X @ W^T + b  (PyTorch Linear layout: W is [out,in]).
// BM=128, BN=64(=HDIM, so each N-block is exactly one head), BK=16,
// 256 threads, 8x4 outputs/thread. Writes [B,H,S,D] layout for attention.
// which==0 (Q) additionally scales by 1/sqrt(64)=0.125 AFTER bias (faithful).
// ---------------------------------------------------------------------------
__global__ __launch_bounds__(256) void proj_kernel(
    const float* __restrict__ X,
    const float* __restrict__ Wq, const float* __restrict__ bq,
    const float* __restrict__ Wk, const float* __restrict__ bk,
    const float* __restrict__ Wv, const float* __restrict__ bv,
    float* __restrict__ Qo, float* __restrict__ Ko, float* __restrict__ Vo)
{
    const int which = blockIdx.z;
    const float* __restrict__ W    = (which == 0) ? Wq : (which == 1) ? Wk : Wv;
    const float* __restrict__ bias = (which == 0) ? bq : (which == 1) ? bk : bv;
    float* __restrict__ out        = (which == 0) ? Qo : (which == 1) ? Ko : Vo;
    const float scale = (which == 0) ? 0.125f : 1.0f;

    __shared__ float Xs[16][128];  // [k][m]
    __shared__ float Ws[16][64];   // [k][n]

    const int t  = threadIdx.x;
    const int m0 = blockIdx.x * 128;
    const int h  = blockIdx.y;     // head index == N-block (BN=64=HDIM)
    const int n0 = h * 64;

    const int tm = t >> 4;         // 0..15 -> rows tm*8 .. tm*8+7
    const int tn = t & 15;         // cols  tn*4 .. tn*4+3

    float acc[8][4];
#pragma unroll
    for (int i = 0; i < 8; ++i)
#pragma unroll
        for (int j = 0; j < 4; ++j) acc[i][j] = 0.f;

    const int xr0 = t >> 2;          // 0..63
    const int xc  = (t & 3) << 2;    // k offset {0,4,8,12}

    for (int k0 = 0; k0 < HIDDEN; k0 += 16) {
        float4 xa = *(const float4*)&X[(size_t)(m0 + xr0)      * HIDDEN + k0 + xc];
        float4 xb = *(const float4*)&X[(size_t)(m0 + xr0 + 64) * HIDDEN + k0 + xc];
        float4 wa = *(const float4*)&W[(size_t)(n0 + xr0)      * HIDDEN + k0 + xc];
        __syncthreads();   // previous iteration's compute done before overwrite
        Xs[xc + 0][xr0] = xa.x; Xs[xc + 1][xr0] = xa.y;
        Xs[xc + 2][xr0] = xa.z; Xs[xc + 3][xr0] = xa.w;
        Xs[xc + 0][xr0 + 64] = xb.x; Xs[xc + 1][xr0 + 64] = xb.y;
        Xs[xc + 2][xr0 + 64] = xb.z; Xs[xc + 3][xr0 + 64] = xb.w;
        Ws[xc + 0][xr0] = wa.x; Ws[xc + 1][xr0] = wa.y;
        Ws[xc + 2][xr0] = wa.z; Ws[xc + 3][xr0] = wa.w;
        __syncthreads();
#pragma unroll
        for (int kk = 0; kk < 16; ++kk) {
            float4 a0 = *(const float4*)&Xs[kk][tm * 8];
            float4 a1 = *(const float4*)&Xs[kk][tm * 8 + 4];
            float4 b0 = *(const float4*)&Ws[kk][tn * 4];
            float av[8] = {a0.x, a0.y, a0.z, a0.w, a1.x, a1.y, a1.z, a1.w};
            float bv4[4] = {b0.x, b0.y, b0.z, b0.w};
#pragma unroll
            for (int i = 0; i < 8; ++i)
#pragma unroll
                for (int j = 0; j < 4; ++j) acc[i][j] += av[i] * bv4[j];
        }
    }

    float4 bfr = *(const float4*)&bias[n0 + tn * 4];
#pragma unroll
    for (int i = 0; i < 8; ++i) {
        int m  = m0 + tm * 8 + i;
        int bb = m >> 11;           // m / SEQ
        int s  = m & (SEQ - 1);
        float4 o;
        o.x = (acc[i][0] + bfr.x) * scale;
        o.y = (acc[i][1] + bfr.y) * scale;
        o.z = (acc[i][2] + bfr.z) * scale;
        o.w = (acc[i][3] + bfr.w) * scale;
        *(float4*)&out[(((size_t)(bb * NHEAD + h) * SEQ) + s) * HDIM + tn * 4] = o;
    }
}

// ---------------------------------------------------------------------------
// Prefix sum of V along sequence per (b,h,d): Vpre[bh][s][d] = sum_{s'<=s} v.
// One block per (b,h); 256 threads = 64 d-lanes x 4 chunks of 512.
// ---------------------------------------------------------------------------
__global__ __launch_bounds__(256) void vprefix_kernel(
    const float* __restrict__ V, float* __restrict__ Vpre)
{
    const int bh    = blockIdx.x;
    const int d     = threadIdx.x & 63;
    const int chunk = threadIdx.x >> 6;   // 0..3
    const float* vb = &V[(size_t)bh * SEQ * HDIM];
    float* pb       = &Vpre[(size_t)bh * SEQ * HDIM];

    __shared__ float csum[4][64];
    const int s0 = chunk * 512;
    float sum = 0.f;
    for (int s = s0; s < s0 + 512; ++s) sum += vb[(size_t)s * HDIM + d];
    csum[chunk][d] = sum;
    __syncthreads();
    float run = 0.f;
    for (int c = 0; c < chunk; ++c) run += csum[c][d];
    for (int s = s0; s < s0 + 512; ++s) {
        run += vb[(size_t)s * HDIM + d];
        pb[(size_t)s * HDIM + d] = run;
    }
}

// ---------------------------------------------------------------------------
// Banded attention with multiplicative-mask-faithful softmax.
// Block = 32 queries x one (b,h). 256 threads: (row r = t>>3, group g = t&7).
// Key tiles of 64 staged in LDS (rows padded to 68 floats: conflict-free).
// Running max inits at 0 (out-of-window zeros always exist), so scale<=1.
// Final:  ctx = (ctx_in + e^{-m} (Vtot - Vwin)) / (l_in + (2048-cnt) e^{-m}).
// ---------------------------------------------------------------------------
__global__ __launch_bounds__(256) void attn_kernel(
    const float* __restrict__ Q, const float* __restrict__ K,
    const float* __restrict__ V, const float* __restrict__ Vpre,
    float* __restrict__ out)
{
    __shared__ float k_lds[64][68];
    __shared__ float v_lds[64][68];
    __shared__ float p_lds[32][68];

    const int t  = threadIdx.x;
    const int bh = blockIdx.y;                 // 0..23
    const int b  = bh / NHEAD;
    const int h  = bh % NHEAD;
    const int i0 = blockIdx.x * 32;
    const int r  = t >> 3;                     // query row 0..31
    const int g  = t & 7;                      // 8-lane group within row
    const int i  = i0 + r;                     // global query index

    // q row into registers (L2-served; 8 threads/row share cachelines)
    const float* qrow = &Q[((size_t)bh * SEQ + i) * HDIM];
    float4 qreg[16];
#pragma unroll
    for (int c = 0; c < 16; ++c) qreg[c] = ((const float4*)qrow)[c];

    float mrun = 0.f, lrun = 0.f;              // max inits at 0: zeros in softmax set
    float4 ctxa = {0, 0, 0, 0}, ctxb = {0, 0, 0, 0};

    const int jlo_blk = (max(0, i0 - WIN)) & ~63;
    const int jhi_blk = min(SEQ - 1, i0 + 31 + WIN);

    for (int jt = jlo_blk; jt <= jhi_blk; jt += 64) {
        __syncthreads();   // prior PV reads complete before overwriting LDS
#pragma unroll
        for (int u = 0; u < 4; ++u) {
            int idx = t + u * 256;             // float4 index 0..1023
            int row = idx >> 4;                // 0..63
            int c4  = idx & 15;
            int js  = min(jt + row, SEQ - 1);  // clamp; masked rows give p=0
            const float4 kv = ((const float4*)&K[((size_t)bh * SEQ + js) * HDIM])[c4];
            const float4 vv = ((const float4*)&V[((size_t)bh * SEQ + js) * HDIM])[c4];
            *(float4*)&k_lds[row][c4 * 4] = kv;
            *(float4*)&v_lds[row][c4 * 4] = vv;
        }
        __syncthreads();

        // ---- scores: this thread handles keys jl = g + 8*kk ----
        float sv[8];
        float tmax = -1e30f;
#pragma unroll
        for (int kk = 0; kk < 8; ++kk) {
            int jl = g + (kk << 3);
            int j  = jt + jl;
            float s = 0.f;
#pragma unroll
            for (int c = 0; c < 16; ++c) {
                int cc = (jl + c) & 15;        // stagger: avoid bank collisions
                float4 kv = *(const float4*)&k_lds[jl][cc * 4];
                float4 qv = qreg[cc];
                s += qv.x * kv.x + qv.y * kv.y + qv.z * kv.z + qv.w * kv.w;
            }
            bool inw = (j >= i - WIN) && (j <= i + WIN) && (j < SEQ);
            sv[kk] = inw ? s : -1e30f;
            tmax = fmaxf(tmax, sv[kk]);
        }
#pragma unroll
        for (int off = 1; off < 8; off <<= 1)
            tmax = fmaxf(tmax, __shfl_xor(tmax, off, 8));

        float m_new = fmaxf(mrun, tmax);       // >= 0 always
        float resc  = __expf(mrun - m_new);
        float lsum  = 0.f;
#pragma unroll
        for (int kk = 0; kk < 8; ++kk) {
            float p = __expf(sv[kk] - m_new);  // masked -> exp(-1e30) == 0
            lsum += p;
            p_lds[r][g + (kk << 3)] = p;
        }
#pragma unroll
        for (int off = 1; off < 8; off <<= 1) lsum += __shfl_xor(lsum, off, 8);
        lrun = lrun * resc + lsum;
        mrun = m_new;
        ctxa.x *= resc; ctxa.y *= resc; ctxa.z *= resc; ctxa.w *= resc;
        ctxb.x *= resc; ctxb.y *= resc; ctxb.z *= resc; ctxb.w *= resc;
        __syncthreads();   // p_lds visible

        // ---- PV: this thread accumulates dims d = g*8 .. g*8+7 for row r ----
#pragma unroll 8
        for (int j = 0; j < 64; ++j) {
            float p   = p_lds[r][j];
            float4 va = *(const float4*)&v_lds[j][g * 8];
            float4 vb = *(const float4*)&v_lds[j][g * 8 + 4];
            ctxa.x += p * va.x; ctxa.y += p * va.y; ctxa.z += p * va.z; ctxa.w += p * va.w;
            ctxb.x += p * vb.x; ctxb.y += p * vb.y; ctxb.z += p * vb.z; ctxb.w += p * vb.w;
        }
    }

    // ---- out-of-window correction + normalize + store ----
    const int jlo = max(0, i - WIN);
    const int jhi = min(SEQ - 1, i + WIN);
    const int cnt = jhi - jlo + 1;
    const float em   = __expf(-mrun);
    const float ltot = lrun + (float)(SEQ - cnt) * em;

    const float* vpT = &Vpre[((size_t)bh * SEQ + (SEQ - 1)) * HDIM];
    const float* vpH = &Vpre[((size_t)bh * SEQ + jhi) * HDIM];
    float4 ta = ((const float4*)vpT)[g * 2],     tb = ((const float4*)vpT)[g * 2 + 1];
    float4 ha = ((const float4*)vpH)[g * 2],     hb = ((const float4*)vpH)[g * 2 + 1];
    float4 la = {0, 0, 0, 0}, lb = {0, 0, 0, 0};
    if (jlo > 0) {
        const float* vpL = &Vpre[((size_t)bh * SEQ + (jlo - 1)) * HDIM];
        la = ((const float4*)vpL)[g * 2];
        lb = ((const float4*)vpL)[g * 2 + 1];
    }
    const float inv = 1.f / ltot;
    float4 oa, ob;
    oa.x = (ctxa.x + em * (ta.x - ha.x + la.x)) * inv;
    oa.y = (ctxa.y + em * (ta.y - ha.y + la.y)) * inv;
    oa.z = (ctxa.z + em * (ta.z - ha.z + la.z)) * inv;
    oa.w = (ctxa.w + em * (ta.w - ha.w + la.w)) * inv;
    ob.x = (ctxb.x + em * (tb.x - hb.x + lb.x)) * inv;
    ob.y = (ctxb.y + em * (tb.y - hb.y + lb.y)) * inv;
    ob.z = (ctxb.z + em * (tb.z - hb.z + lb.z)) * inv;
    ob.w = (ctxb.w + em * (tb.w - hb.w + lb.w)) * inv;

    float* op = &out[((size_t)(b * SEQ + i)) * HIDDEN + h * HDIM + g * 8];
    ((float4*)op)[0] = oa;
    ((float4*)op)[1] = ob;
}

// ---------------------------------------------------------------------------
extern "C" void kernel_launch(void* const* d_in, const int* in_sizes, int n_in,
                              void* d_out, int out_size, void* d_ws, size_t ws_size,
                              hipStream_t stream) {
    const float* X  = (const float*)d_in[0];
    const float* Wq = (const float*)d_in[1];
    const float* bq = (const float*)d_in[2];
    const float* Wk = (const float*)d_in[3];
    const float* bk = (const float*)d_in[4];
    const float* Wv = (const float*)d_in[5];
    const float* bv = (const float*)d_in[6];
    float* out = (float*)d_out;

    const size_t TEN = (size_t)BATCH * NHEAD * SEQ * HDIM;  // 3,145,728 floats
    float* qf   = (float*)d_ws;
    float* kf   = qf + TEN;
    float* vf   = kf + TEN;
    float* vpre = vf + TEN;   // total 48 MB of ws

    proj_kernel<<<dim3(MTOT / 128, NHEAD, 3), 256, 0, stream>>>(
        X, Wq, bq, Wk, bk, Wv, bv, qf, kf, vf);
    vprefix_kernel<<<dim3(BATCH * NHEAD), 256, 0, stream>>>(vf, vpre);
    attn_kernel<<<dim3(SEQ / 32, BATCH * NHEAD), 256, 0, stream>>>(
        qf, kf, vf, vpre, out);
}

// Round 2
// 739.011 us; speedup vs baseline: 1.0016x; 1.0016x over previous
//
#include <hip/hip_runtime.h>
#include <hip/hip_bf16.h>
#include <cstdint>

// Problem constants (LongformerSelfAttention: B=2, S=2048, M=768, H=12, D=64, W=256, DIL=1)
#define SEQ    2048
#define HIDDEN 768
#define NHEAD  12
#define HDIM   64
#define WIN    256
#define BATCH  2
#define MTOT   (BATCH * SEQ)   // 4096 tokens

// ---------------------------------------------------------------------------
// Projection GEMM: Y = X @ W^T + b  (PyTorch Linear layout: W is [out,in]).
// BM=128, BN=64(=HDIM, so each N-block is exactly one head), BK=16,
// 256 threads, 8x4 outputs/thread. Writes [B,H,S,D] layout for attention.
// which==0 (Q) additionally scales by 1/sqrt(64)=0.125 AFTER bias (faithful).
// ---------------------------------------------------------------------------
__global__ __launch_bounds__(256) void proj_kernel(
    const float* __restrict__ X,
    const float* __restrict__ Wq, const float* __restrict__ bq,
    const float* __restrict__ Wk, const float* __restrict__ bk,
    const float* __restrict__ Wv, const float* __restrict__ bv,
    float* __restrict__ Qo, float* __restrict__ Ko, float* __restrict__ Vo)
{
    const int which = blockIdx.z;
    const float* __restrict__ W    = (which == 0) ? Wq : (which == 1) ? Wk : Wv;
    const float* __restrict__ bias = (which == 0) ? bq : (which == 1) ? bk : bv;
    float* __restrict__ out        = (which == 0) ? Qo : (which == 1) ? Ko : Vo;
    const float scale = (which == 0) ? 0.125f : 1.0f;

    __shared__ float Xs[16][128];  // [k][m]
    __shared__ float Ws[16][64];   // [k][n]

    const int t  = threadIdx.x;
    const int m0 = blockIdx.x * 128;
    const int h  = blockIdx.y;     // head index == N-block (BN=64=HDIM)
    const int n0 = h * 64;

    const int tm = t >> 4;         // 0..15 -> rows tm*8 .. tm*8+7
    const int tn = t & 15;         // cols  tn*4 .. tn*4+3

    float acc[8][4];
#pragma unroll
    for (int i = 0; i < 8; ++i)
#pragma unroll
        for (int j = 0; j < 4; ++j) acc[i][j] = 0.f;

    const int xr0 = t >> 2;          // 0..63
    const int xc  = (t & 3) << 2;    // k offset {0,4,8,12}

    for (int k0 = 0; k0 < HIDDEN; k0 += 16) {
        float4 xa = *(const float4*)&X[(size_t)(m0 + xr0)      * HIDDEN + k0 + xc];
        float4 xb = *(const float4*)&X[(size_t)(m0 + xr0 + 64) * HIDDEN + k0 + xc];
        float4 wa = *(const float4*)&W[(size_t)(n0 + xr0)      * HIDDEN + k0 + xc];
        __syncthreads();   // previous iteration's compute done before overwrite
        Xs[xc + 0][xr0] = xa.x; Xs[xc + 1][xr0] = xa.y;
        Xs[xc + 2][xr0] = xa.z; Xs[xc + 3][xr0] = xa.w;
        Xs[xc + 0][xr0 + 64] = xb.x; Xs[xc + 1][xr0 + 64] = xb.y;
        Xs[xc + 2][xr0 + 64] = xb.z; Xs[xc + 3][xr0 + 64] = xb.w;
        Ws[xc + 0][xr0] = wa.x; Ws[xc + 1][xr0] = wa.y;
        Ws[xc + 2][xr0] = wa.z; Ws[xc + 3][xr0] = wa.w;
        __syncthreads();
#pragma unroll
        for (int kk = 0; kk < 16; ++kk) {
            float4 a0 = *(const float4*)&Xs[kk][tm * 8];
            float4 a1 = *(const float4*)&Xs[kk][tm * 8 + 4];
            float4 b0 = *(const float4*)&Ws[kk][tn * 4];
            float av[8] = {a0.x, a0.y, a0.z, a0.w, a1.x, a1.y, a1.z, a1.w};
            float bv4[4] = {b0.x, b0.y, b0.z, b0.w};
#pragma unroll
            for (int i = 0; i < 8; ++i)
#pragma unroll
                for (int j = 0; j < 4; ++j) acc[i][j] += av[i] * bv4[j];
        }
    }

    float4 bfr = *(const float4*)&bias[n0 + tn * 4];
#pragma unroll
    for (int i = 0; i < 8; ++i) {
        int m  = m0 + tm * 8 + i;
        int bb = m >> 11;           // m / SEQ
        int s  = m & (SEQ - 1);
        float4 o;
        o.x = (acc[i][0] + bfr.x) * scale;
        o.y = (acc[i][1] + bfr.y) * scale;
        o.z = (acc[i][2] + bfr.z) * scale;
        o.w = (acc[i][3] + bfr.w) * scale;
        *(float4*)&out[(((size_t)(bb * NHEAD + h) * SEQ) + s) * HDIM + tn * 4] = o;
    }
}

// ---------------------------------------------------------------------------
// Prefix sum of V along sequence per (b,h,d): Vpre[bh][s][d] = sum_{s'<=s} v.
// ---------------------------------------------------------------------------
__global__ __launch_bounds__(256) void vprefix_kernel(
    const float* __restrict__ V, float* __restrict__ Vpre)
{
    const int bh    = blockIdx.x;
    const int d     = threadIdx.x & 63;
    const int chunk = threadIdx.x >> 6;   // 0..3
    const float* vb = &V[(size_t)bh * SEQ * HDIM];
    float* pb       = &Vpre[(size_t)bh * SEQ * HDIM];

    __shared__ float csum[4][64];
    const int s0 = chunk * 512;
    float sum = 0.f;
    for (int s = s0; s < s0 + 512; ++s) sum += vb[(size_t)s * HDIM + d];
    csum[chunk][d] = sum;
    __syncthreads();
    float run = 0.f;
    for (int c = 0; c < chunk; ++c) run += csum[c][d];
    for (int s = s0; s < s0 + 512; ++s) {
        run += vb[(size_t)s * HDIM + d];
        pb[(size_t)s * HDIM + d] = run;
    }
}

// ---------------------------------------------------------------------------
// Banded attention v2.
//  - QBLK=64 queries/block, 512 threads (thread = (r = t>>3 in 0..63, g = t&7)).
//  - XCD-aware block swizzle: xcd = L&7 owns bh = xcd*3 + slot/32, contiguous
//    q-blocks in slot order -> per-XCD L2 working set ~4 MB, streaming.
//  - Async-STAGE split (T14): issue next K/V tile's global loads into regs
//    before compute, ds-write after the post-compute barrier.
//  - 2 barriers/tile: p_lds rows are produced and consumed by the same wave.
// Softmax faithful to multiplicative mask: running max inits at 0; final
// out-of-window correction via Vpre prefix sums.
// ---------------------------------------------------------------------------
__global__ __launch_bounds__(512, 4) void attn_kernel(
    const float* __restrict__ Q, const float* __restrict__ K,
    const float* __restrict__ V, const float* __restrict__ Vpre,
    float* __restrict__ out)
{
    __shared__ float k_lds[64][68];
    __shared__ float v_lds[64][68];
    __shared__ float p_lds[64][68];

    const int t    = threadIdx.x;
    const int L    = blockIdx.x;
    const int xcd  = L & 7;
    const int slot = L >> 3;                   // 0..95
    const int bh   = xcd * 3 + (slot >> 5);    // 0..23
    const int qb   = slot & 31;                // 0..31
    const int b    = bh / NHEAD;
    const int h    = bh % NHEAD;
    const int i0   = qb * 64;
    const int r    = t >> 3;                   // query row 0..63 (wave-private p rows)
    const int g    = t & 7;                    // 8-lane group within row
    const int i    = i0 + r;                   // global query index

    // q row into registers
    const float* qrow = &Q[((size_t)bh * SEQ + i) * HDIM];
    float4 qreg[16];
#pragma unroll
    for (int c = 0; c < 16; ++c) qreg[c] = ((const float4*)qrow)[c];

    float mrun = 0.f, lrun = 0.f;              // max inits at 0: mask zeros always present
    float4 ctxa = {0, 0, 0, 0}, ctxb = {0, 0, 0, 0};

    const int jlo_blk = max(0, i0 - WIN);      // i0 mult of 64 -> already tile-aligned
    const int jhi_blk = min(SEQ - 1, i0 + 63 + WIN);

    const float* kbase = &K[(size_t)bh * SEQ * HDIM];
    const float* vbase = &V[(size_t)bh * SEQ * HDIM];

    // staging slots: this thread covers float4 idx {t, t+512} of the 64x16 tile
    const int srow0 = t >> 4;                  // 0..31
    const int sc4   = t & 15;
    float4 kpre[2], vpre4[2];

    // ---- preload tile 0 ----
    {
        int js0 = min(jlo_blk + srow0, SEQ - 1);
        int js1 = min(jlo_blk + srow0 + 32, SEQ - 1);
        kpre[0] = ((const float4*)&kbase[(size_t)js0 * HDIM])[sc4];
        vpre4[0] = ((const float4*)&vbase[(size_t)js0 * HDIM])[sc4];
        kpre[1] = ((const float4*)&kbase[(size_t)js1 * HDIM])[sc4];
        vpre4[1] = ((const float4*)&vbase[(size_t)js1 * HDIM])[sc4];
        *(float4*)&k_lds[srow0][sc4 * 4]      = kpre[0];
        *(float4*)&v_lds[srow0][sc4 * 4]      = vpre4[0];
        *(float4*)&k_lds[srow0 + 32][sc4 * 4] = kpre[1];
        *(float4*)&v_lds[srow0 + 32][sc4 * 4] = vpre4[1];
    }

    for (int jt = jlo_blk; jt <= jhi_blk; jt += 64) {
        const bool more = (jt + 64) <= jhi_blk;
        if (more) {   // issue next tile's loads; latency hides under compute
            int js0 = min(jt + 64 + srow0, SEQ - 1);
            int js1 = min(jt + 64 + srow0 + 32, SEQ - 1);
            kpre[0] = ((const float4*)&kbase[(size_t)js0 * HDIM])[sc4];
            vpre4[0] = ((const float4*)&vbase[(size_t)js0 * HDIM])[sc4];
            kpre[1] = ((const float4*)&kbase[(size_t)js1 * HDIM])[sc4];
            vpre4[1] = ((const float4*)&vbase[(size_t)js1 * HDIM])[sc4];
        }
        __syncthreads();   // current tile's LDS writes visible

        // ---- scores: this thread handles keys jl = g + 8*kk ----
        float sv[8];
        float tmax = -1e30f;
#pragma unroll
        for (int kk = 0; kk < 8; ++kk) {
            int jl = g + (kk << 3);
            int j  = jt + jl;
            float s = 0.f;
#pragma unroll
            for (int c = 0; c < 16; ++c) {
                int cc = (jl + c) & 15;        // stagger: avoid bank collisions
                float4 kv = *(const float4*)&k_lds[jl][cc * 4];
                float4 qv = qreg[cc];
                s += qv.x * kv.x + qv.y * kv.y + qv.z * kv.z + qv.w * kv.w;
            }
            bool inw = (j >= i - WIN) && (j <= i + WIN) && (j < SEQ);
            sv[kk] = inw ? s : -1e30f;
            tmax = fmaxf(tmax, sv[kk]);
        }
#pragma unroll
        for (int off = 1; off < 8; off <<= 1)
            tmax = fmaxf(tmax, __shfl_xor(tmax, off, 8));

        float m_new = fmaxf(mrun, tmax);       // >= 0 always
        float resc  = __expf(mrun - m_new);
        float lsum  = 0.f;
#pragma unroll
        for (int kk = 0; kk < 8; ++kk) {
            float p = __expf(sv[kk] - m_new);  // masked -> 0
            lsum += p;
            p_lds[r][g + (kk << 3)] = p;       // row r: produced+consumed by this wave only
        }
#pragma unroll
        for (int off = 1; off < 8; off <<= 1) lsum += __shfl_xor(lsum, off, 8);
        lrun = lrun * resc + lsum;
        mrun = m_new;
        ctxa.x *= resc; ctxa.y *= resc; ctxa.z *= resc; ctxa.w *= resc;
        ctxb.x *= resc; ctxb.y *= resc; ctxb.z *= resc; ctxb.w *= resc;

        // ---- PV: dims d = g*8 .. g*8+7 for row r (no barrier: same-wave p rows) ----
#pragma unroll 8
        for (int j = 0; j < 64; ++j) {
            float p   = p_lds[r][j];
            float4 va = *(const float4*)&v_lds[j][g * 8];
            float4 vb = *(const float4*)&v_lds[j][g * 8 + 4];
            ctxa.x += p * va.x; ctxa.y += p * va.y; ctxa.z += p * va.z; ctxa.w += p * va.w;
            ctxb.x += p * vb.x; ctxb.y += p * vb.y; ctxb.z += p * vb.z; ctxb.w += p * vb.w;
        }

        __syncthreads();   // all reads of this tile done
        if (more) {        // commit prefetched tile to LDS
            *(float4*)&k_lds[srow0][sc4 * 4]      = kpre[0];
            *(float4*)&v_lds[srow0][sc4 * 4]      = vpre4[0];
            *(float4*)&k_lds[srow0 + 32][sc4 * 4] = kpre[1];
            *(float4*)&v_lds[srow0 + 32][sc4 * 4] = vpre4[1];
        }
    }

    // ---- out-of-window correction + normalize + store ----
    const int jlo = max(0, i - WIN);
    const int jhi = min(SEQ - 1, i + WIN);
    const int cnt = jhi - jlo + 1;
    const float em   = __expf(-mrun);
    const float ltot = lrun + (float)(SEQ - cnt) * em;

    const float* vpT = &Vpre[((size_t)bh * SEQ + (SEQ - 1)) * HDIM];
    const float* vpH = &Vpre[((size_t)bh * SEQ + jhi) * HDIM];
    float4 ta = ((const float4*)vpT)[g * 2],     tb = ((const float4*)vpT)[g * 2 + 1];
    float4 ha = ((const float4*)vpH)[g * 2],     hb = ((const float4*)vpH)[g * 2 + 1];
    float4 la = {0, 0, 0, 0}, lb = {0, 0, 0, 0};
    if (jlo > 0) {
        const float* vpL = &Vpre[((size_t)bh * SEQ + (jlo - 1)) * HDIM];
        la = ((const float4*)vpL)[g * 2];
        lb = ((const float4*)vpL)[g * 2 + 1];
    }
    const float inv = 1.f / ltot;
    float4 oa, ob;
    oa.x = (ctxa.x + em * (ta.x - ha.x + la.x)) * inv;
    oa.y = (ctxa.y + em * (ta.y - ha.y + la.y)) * inv;
    oa.z = (ctxa.z + em * (ta.z - ha.z + la.z)) * inv;
    oa.w = (ctxa.w + em * (ta.w - ha.w + la.w)) * inv;
    ob.x = (ctxb.x + em * (tb.x - hb.x + lb.x)) * inv;
    ob.y = (ctxb.y + em * (tb.y - hb.y + lb.y)) * inv;
    ob.z = (ctxb.z + em * (tb.z - hb.z + lb.z)) * inv;
    ob.w = (ctxb.w + em * (tb.w - hb.w + lb.w)) * inv;

    float* op = &out[((size_t)(b * SEQ + i)) * HIDDEN + h * HDIM + g * 8];
    ((float4*)op)[0] = oa;
    ((float4*)op)[1] = ob;
}

// ---------------------------------------------------------------------------
extern "C" void kernel_launch(void* const* d_in, const int* in_sizes, int n_in,
                              void* d_out, int out_size, void* d_ws, size_t ws_size,
                              hipStream_t stream) {
    const float* X  = (const float*)d_in[0];
    const float* Wq = (const float*)d_in[1];
    const float* bq = (const float*)d_in[2];
    const float* Wk = (const float*)d_in[3];
    const float* bk = (const float*)d_in[4];
    const float* Wv = (const float*)d_in[5];
    const float* bv = (const float*)d_in[6];
    float* out = (float*)d_out;

    const size_t TEN = (size_t)BATCH * NHEAD * SEQ * HDIM;  // 3,145,728 floats
    float* qf   = (float*)d_ws;
    float* kf   = qf + TEN;
    float* vf   = kf + TEN;
    float* vpre = vf + TEN;   // total 48 MB of ws

    proj_kernel<<<dim3(MTOT / 128, NHEAD, 3), 256, 0, stream>>>(
        X, Wq, bq, Wk, bk, Wv, bv, qf, kf, vf);
    vprefix_kernel<<<dim3(BATCH * NHEAD), 256, 0, stream>>>(vf, vpre);
    attn_kernel<<<dim3((SEQ / 64) * BATCH * NHEAD), 512, 0, stream>>>(
        qf, kf, vf, vpre, out);
}

// Round 3
// 596.925 us; speedup vs baseline: 1.2400x; 1.2380x over previous
//
#include <hip/hip_runtime.h>
#include <hip/hip_bf16.h>
#include <cstdint>

// Problem constants (LongformerSelfAttention: B=2, S=2048, M=768, H=12, D=64, W=256, DIL=1)
#define SEQ    2048
#define HIDDEN 768
#define NHEAD  12
#define HDIM   64
#define WIN    256
#define BATCH  2
#define MTOT   (BATCH * SEQ)   // 4096 tokens

typedef __attribute__((ext_vector_type(8))) short short8;   // 8 bf16 = 4 VGPR (MFMA A/B frag)
typedef __attribute__((ext_vector_type(4))) float f32x4;    // MFMA C/D frag

__device__ __forceinline__ ushort bf16_rne(float f) {
    uint u = __float_as_uint(f);
    uint r = u + 0x7FFFu + ((u >> 16) & 1u);   // round-to-nearest-even; inputs are normal
    return (ushort)(r >> 16);
}
__device__ __forceinline__ float bf16_to_f(ushort h) {
    return __uint_as_float(((uint)h) << 16);
}

// ---------------------------------------------------------------------------
// Projection GEMM via split-bf16 MFMA:  Y = X @ W^T + b  (W is [out,in]).
//   x = xhi + xlo (bf16 each, |xlo| <= 2^-9 |x|);  x*w ~= xhi*whi + xhi*wlo
//   + xlo*whi  (error ~2^-18 relative)  -> 3x mfma_f32_16x16x32_bf16.
// BM=128, BN=64 (= one head), BK=64, 256 threads = 4 waves in 2x2.
// fp32->hi/lo conversion happens in-kernel during LDS staging (no extra ws).
// LDS XOR swizzle (G4): ushort idx ^= (row&7)<<3  — spreads the 16-row
// fragment read across all 8 16B-units of the 32-bank line (conflict-free).
// which==0 (Q) scales by 1/sqrt(64)=0.125 after bias (faithful to ref).
// Writes [B,H,S,D] fp32 layout for the attention kernel.
// ---------------------------------------------------------------------------
__global__ __launch_bounds__(256) void proj_mfma_kernel(
    const float* __restrict__ X,
    const float* __restrict__ Wq, const float* __restrict__ bq,
    const float* __restrict__ Wk, const float* __restrict__ bk,
    const float* __restrict__ Wv, const float* __restrict__ bv,
    float* __restrict__ Qo, float* __restrict__ Ko, float* __restrict__ Vo)
{
    const int which = blockIdx.z;
    const float* __restrict__ W    = (which == 0) ? Wq : (which == 1) ? Wk : Wv;
    const float* __restrict__ bias = (which == 0) ? bq : (which == 1) ? bk : bv;
    float* __restrict__ out        = (which == 0) ? Qo : (which == 1) ? Ko : Vo;
    const float scale = (which == 0) ? 0.125f : 1.0f;

    __shared__ __align__(16) ushort Ahi[128 * 64];
    __shared__ __align__(16) ushort Alo[128 * 64];
    __shared__ __align__(16) ushort Bhi[64 * 64];
    __shared__ __align__(16) ushort Blo[64 * 64];

    const int t  = threadIdx.x;
    const int m0 = blockIdx.x * 128;
    const int h  = blockIdx.y;            // head == N-block (BN=64=HDIM)
    const int n0 = h * 64;

    const int w    = t >> 6;              // wave 0..3
    const int lane = t & 63;
    const int wr   = w >> 1;              // wave row 0..1  (64 M-rows each)
    const int wc   = w & 1;               // wave col 0..1  (32 N-cols each)
    const int lr   = lane & 15;           // frag row/col (m for A, n for B/C-col)
    const int lk   = lane >> 4;           // k-chunk 0..3 (8 bf16 each)

    f32x4 acc[4][2];
#pragma unroll
    for (int i = 0; i < 4; ++i)
#pragma unroll
        for (int j = 0; j < 2; ++j) acc[i][j] = (f32x4){0.f, 0.f, 0.f, 0.f};

    for (int k0 = 0; k0 < HIDDEN; k0 += 64) {
        __syncthreads();   // previous iteration's frag reads done
        // ---- stage + convert A tile: 128 rows x 64 k (8 float4 / thread) ----
#pragma unroll
        for (int i = 0; i < 8; ++i) {
            int id  = t + i * 256;          // float4 id 0..2047
            int row = id >> 4;
            int c4  = id & 15;
            const float4 xv = *(const float4*)&X[(size_t)(m0 + row) * HIDDEN + k0 + c4 * 4];
            ushort h0 = bf16_rne(xv.x), h1 = bf16_rne(xv.y),
                   h2 = bf16_rne(xv.z), h3 = bf16_rne(xv.w);
            ushort l0 = bf16_rne(xv.x - bf16_to_f(h0)),
                   l1 = bf16_rne(xv.y - bf16_to_f(h1)),
                   l2 = bf16_rne(xv.z - bf16_to_f(h2)),
                   l3 = bf16_rne(xv.w - bf16_to_f(h3));
            int idx = (row * 64 + c4 * 4) ^ ((row & 7) << 3);
            *(uint2*)&Ahi[idx] = make_uint2((uint)h0 | ((uint)h1 << 16),
                                            (uint)h2 | ((uint)h3 << 16));
            *(uint2*)&Alo[idx] = make_uint2((uint)l0 | ((uint)l1 << 16),
                                            (uint)l2 | ((uint)l3 << 16));
        }
        // ---- stage + convert B tile: 64 rows x 64 k (4 float4 / thread) ----
#pragma unroll
        for (int i = 0; i < 4; ++i) {
            int id  = t + i * 256;          // float4 id 0..1023
            int row = id >> 4;
            int c4  = id & 15;
            const float4 wv = *(const float4*)&W[(size_t)(n0 + row) * HIDDEN + k0 + c4 * 4];
            ushort h0 = bf16_rne(wv.x), h1 = bf16_rne(wv.y),
                   h2 = bf16_rne(wv.z), h3 = bf16_rne(wv.w);
            ushort l0 = bf16_rne(wv.x - bf16_to_f(h0)),
                   l1 = bf16_rne(wv.y - bf16_to_f(h1)),
                   l2 = bf16_rne(wv.z - bf16_to_f(h2)),
                   l3 = bf16_rne(wv.w - bf16_to_f(h3));
            int idx = (row * 64 + c4 * 4) ^ ((row & 7) << 3);
            *(uint2*)&Bhi[idx] = make_uint2((uint)h0 | ((uint)h1 << 16),
                                            (uint)h2 | ((uint)h3 << 16));
            *(uint2*)&Blo[idx] = make_uint2((uint)l0 | ((uint)l1 << 16),
                                            (uint)l2 | ((uint)l3 << 16));
        }
        __syncthreads();

        // ---- MFMA: 2 k-steps of 32; 4x2 frags; 3 split-products each ----
#pragma unroll
        for (int s = 0; s < 2; ++s) {
            short8 ah[4], al[4], bh[2], bl[2];
#pragma unroll
            for (int fm = 0; fm < 4; ++fm) {
                int row = wr * 64 + fm * 16 + lr;
                int idx = (row * 64 + s * 32 + lk * 8) ^ ((row & 7) << 3);
                ah[fm] = *(const short8*)&Ahi[idx];
                al[fm] = *(const short8*)&Alo[idx];
            }
#pragma unroll
            for (int fn = 0; fn < 2; ++fn) {
                int row = wc * 32 + fn * 16 + lr;
                int idx = (row * 64 + s * 32 + lk * 8) ^ ((row & 7) << 3);
                bh[fn] = *(const short8*)&Bhi[idx];
                bl[fn] = *(const short8*)&Blo[idx];
            }
#pragma unroll
            for (int fm = 0; fm < 4; ++fm)
#pragma unroll
                for (int fn = 0; fn < 2; ++fn) {
                    acc[fm][fn] = __builtin_amdgcn_mfma_f32_16x16x32_bf16(
                        ah[fm], bh[fn], acc[fm][fn], 0, 0, 0);
                    acc[fm][fn] = __builtin_amdgcn_mfma_f32_16x16x32_bf16(
                        ah[fm], bl[fn], acc[fm][fn], 0, 0, 0);
                    acc[fm][fn] = __builtin_amdgcn_mfma_f32_16x16x32_bf16(
                        al[fm], bh[fn], acc[fm][fn], 0, 0, 0);
                }
        }
    }

    // ---- epilogue: C/D layout col=lane&15, row=(lane>>4)*4+reg (m89/m91) ----
#pragma unroll
    for (int fn = 0; fn < 2; ++fn) {
        int d = wc * 32 + fn * 16 + lr;
        float bval = bias[n0 + d];
#pragma unroll
        for (int fm = 0; fm < 4; ++fm) {
#pragma unroll
            for (int r = 0; r < 4; ++r) {
                int m  = m0 + wr * 64 + fm * 16 + lk * 4 + r;
                int bb = m >> 11;            // m / SEQ
                int ss = m & (SEQ - 1);
                out[(((size_t)(bb * NHEAD + h) * SEQ) + ss) * HDIM + d] =
                    (acc[fm][fn][r] + bval) * scale;
            }
        }
    }
}

// ---------------------------------------------------------------------------
// Prefix sum of V along sequence per (b,h,d): Vpre[bh][s][d] = sum_{s'<=s} v.
// ---------------------------------------------------------------------------
__global__ __launch_bounds__(256) void vprefix_kernel(
    const float* __restrict__ V, float* __restrict__ Vpre)
{
    const int bh    = blockIdx.x;
    const int d     = threadIdx.x & 63;
    const int chunk = threadIdx.x >> 6;   // 0..3
    const float* vb = &V[(size_t)bh * SEQ * HDIM];
    float* pb       = &Vpre[(size_t)bh * SEQ * HDIM];

    __shared__ float csum[4][64];
    const int s0 = chunk * 512;
    float sum = 0.f;
    for (int s = s0; s < s0 + 512; ++s) sum += vb[(size_t)s * HDIM + d];
    csum[chunk][d] = sum;
    __syncthreads();
    float run = 0.f;
    for (int c = 0; c < chunk; ++c) run += csum[c][d];
    for (int s = s0; s < s0 + 512; ++s) {
        run += vb[(size_t)s * HDIM + d];
        pb[(size_t)s * HDIM + d] = run;
    }
}

// ---------------------------------------------------------------------------
// Banded attention (unchanged from round 2 — kept byte-identical so the
// proj rewrite's effect is cleanly attributable; MFMA port is next).
// ---------------------------------------------------------------------------
__global__ __launch_bounds__(512, 4) void attn_kernel(
    const float* __restrict__ Q, const float* __restrict__ K,
    const float* __restrict__ V, const float* __restrict__ Vpre,
    float* __restrict__ out)
{
    __shared__ float k_lds[64][68];
    __shared__ float v_lds[64][68];
    __shared__ float p_lds[64][68];

    const int t    = threadIdx.x;
    const int L    = blockIdx.x;
    const int xcd  = L & 7;
    const int slot = L >> 3;                   // 0..95
    const int bh   = xcd * 3 + (slot >> 5);    // 0..23
    const int qb   = slot & 31;                // 0..31
    const int b    = bh / NHEAD;
    const int h    = bh % NHEAD;
    const int i0   = qb * 64;
    const int r    = t >> 3;                   // query row 0..63 (wave-private p rows)
    const int g    = t & 7;                    // 8-lane group within row
    const int i    = i0 + r;                   // global query index

    const float* qrow = &Q[((size_t)bh * SEQ + i) * HDIM];
    float4 qreg[16];
#pragma unroll
    for (int c = 0; c < 16; ++c) qreg[c] = ((const float4*)qrow)[c];

    float mrun = 0.f, lrun = 0.f;              // max inits at 0: mask zeros always present
    float4 ctxa = {0, 0, 0, 0}, ctxb = {0, 0, 0, 0};

    const int jlo_blk = max(0, i0 - WIN);
    const int jhi_blk = min(SEQ - 1, i0 + 63 + WIN);

    const float* kbase = &K[(size_t)bh * SEQ * HDIM];
    const float* vbase = &V[(size_t)bh * SEQ * HDIM];

    const int srow0 = t >> 4;                  // 0..31
    const int sc4   = t & 15;
    float4 kpre[2], vpre4[2];

    {
        int js0 = min(jlo_blk + srow0, SEQ - 1);
        int js1 = min(jlo_blk + srow0 + 32, SEQ - 1);
        kpre[0] = ((const float4*)&kbase[(size_t)js0 * HDIM])[sc4];
        vpre4[0] = ((const float4*)&vbase[(size_t)js0 * HDIM])[sc4];
        kpre[1] = ((const float4*)&kbase[(size_t)js1 * HDIM])[sc4];
        vpre4[1] = ((const float4*)&vbase[(size_t)js1 * HDIM])[sc4];
        *(float4*)&k_lds[srow0][sc4 * 4]      = kpre[0];
        *(float4*)&v_lds[srow0][sc4 * 4]      = vpre4[0];
        *(float4*)&k_lds[srow0 + 32][sc4 * 4] = kpre[1];
        *(float4*)&v_lds[srow0 + 32][sc4 * 4] = vpre4[1];
    }

    for (int jt = jlo_blk; jt <= jhi_blk; jt += 64) {
        const bool more = (jt + 64) <= jhi_blk;
        if (more) {
            int js0 = min(jt + 64 + srow0, SEQ - 1);
            int js1 = min(jt + 64 + srow0 + 32, SEQ - 1);
            kpre[0] = ((const float4*)&kbase[(size_t)js0 * HDIM])[sc4];
            vpre4[0] = ((const float4*)&vbase[(size_t)js0 * HDIM])[sc4];
            kpre[1] = ((const float4*)&kbase[(size_t)js1 * HDIM])[sc4];
            vpre4[1] = ((const float4*)&vbase[(size_t)js1 * HDIM])[sc4];
        }
        __syncthreads();

        float sv[8];
        float tmax = -1e30f;
#pragma unroll
        for (int kk = 0; kk < 8; ++kk) {
            int jl = g + (kk << 3);
            int j  = jt + jl;
            float s = 0.f;
#pragma unroll
            for (int c = 0; c < 16; ++c) {
                int cc = (jl + c) & 15;
                float4 kv = *(const float4*)&k_lds[jl][cc * 4];
                float4 qv = qreg[cc];
                s += qv.x * kv.x + qv.y * kv.y + qv.z * kv.z + qv.w * kv.w;
            }
            bool inw = (j >= i - WIN) && (j <= i + WIN) && (j < SEQ);
            sv[kk] = inw ? s : -1e30f;
            tmax = fmaxf(tmax, sv[kk]);
        }
#pragma unroll
        for (int off = 1; off < 8; off <<= 1)
            tmax = fmaxf(tmax, __shfl_xor(tmax, off, 8));

        float m_new = fmaxf(mrun, tmax);
        float resc  = __expf(mrun - m_new);
        float lsum  = 0.f;
#pragma unroll
        for (int kk = 0; kk < 8; ++kk) {
            float p = __expf(sv[kk] - m_new);
            lsum += p;
            p_lds[r][g + (kk << 3)] = p;
        }
#pragma unroll
        for (int off = 1; off < 8; off <<= 1) lsum += __shfl_xor(lsum, off, 8);
        lrun = lrun * resc + lsum;
        mrun = m_new;
        ctxa.x *= resc; ctxa.y *= resc; ctxa.z *= resc; ctxa.w *= resc;
        ctxb.x *= resc; ctxb.y *= resc; ctxb.z *= resc; ctxb.w *= resc;

#pragma unroll 8
        for (int j = 0; j < 64; ++j) {
            float p   = p_lds[r][j];
            float4 va = *(const float4*)&v_lds[j][g * 8];
            float4 vb = *(const float4*)&v_lds[j][g * 8 + 4];
            ctxa.x += p * va.x; ctxa.y += p * va.y; ctxa.z += p * va.z; ctxa.w += p * va.w;
            ctxb.x += p * vb.x; ctxb.y += p * vb.y; ctxb.z += p * vb.z; ctxb.w += p * vb.w;
        }

        __syncthreads();
        if (more) {
            *(float4*)&k_lds[srow0][sc4 * 4]      = kpre[0];
            *(float4*)&v_lds[srow0][sc4 * 4]      = vpre4[0];
            *(float4*)&k_lds[srow0 + 32][sc4 * 4] = kpre[1];
            *(float4*)&v_lds[srow0 + 32][sc4 * 4] = vpre4[1];
        }
    }

    const int jlo = max(0, i - WIN);
    const int jhi = min(SEQ - 1, i + WIN);
    const int cnt = jhi - jlo + 1;
    const float em   = __expf(-mrun);
    const float ltot = lrun + (float)(SEQ - cnt) * em;

    const float* vpT = &Vpre[((size_t)bh * SEQ + (SEQ - 1)) * HDIM];
    const float* vpH = &Vpre[((size_t)bh * SEQ + jhi) * HDIM];
    float4 ta = ((const float4*)vpT)[g * 2],     tb = ((const float4*)vpT)[g * 2 + 1];
    float4 ha = ((const float4*)vpH)[g * 2],     hb = ((const float4*)vpH)[g * 2 + 1];
    float4 la = {0, 0, 0, 0}, lb = {0, 0, 0, 0};
    if (jlo > 0) {
        const float* vpL = &Vpre[((size_t)bh * SEQ + (jlo - 1)) * HDIM];
        la = ((const float4*)vpL)[g * 2];
        lb = ((const float4*)vpL)[g * 2 + 1];
    }
    const float inv = 1.f / ltot;
    float4 oa, ob;
    oa.x = (ctxa.x + em * (ta.x - ha.x + la.x)) * inv;
    oa.y = (ctxa.y + em * (ta.y - ha.y + la.y)) * inv;
    oa.z = (ctxa.z + em * (ta.z - ha.z + la.z)) * inv;
    oa.w = (ctxa.w + em * (ta.w - ha.w + la.w)) * inv;
    ob.x = (ctxb.x + em * (tb.x - hb.x + lb.x)) * inv;
    ob.y = (ctxb.y + em * (tb.y - hb.y + lb.y)) * inv;
    ob.z = (ctxb.z + em * (tb.z - hb.z + lb.z)) * inv;
    ob.w = (ctxb.w + em * (tb.w - hb.w + lb.w)) * inv;

    float* op = &out[((size_t)(b * SEQ + i)) * HIDDEN + h * HDIM + g * 8];
    ((float4*)op)[0] = oa;
    ((float4*)op)[1] = ob;
}

// ---------------------------------------------------------------------------
extern "C" void kernel_launch(void* const* d_in, const int* in_sizes, int n_in,
                              void* d_out, int out_size, void* d_ws, size_t ws_size,
                              hipStream_t stream) {
    const float* X  = (const float*)d_in[0];
    const float* Wq = (const float*)d_in[1];
    const float* bq = (const float*)d_in[2];
    const float* Wk = (const float*)d_in[3];
    const float* bk = (const float*)d_in[4];
    const float* Wv = (const float*)d_in[5];
    const float* bv = (const float*)d_in[6];
    float* out = (float*)d_out;

    const size_t TEN = (size_t)BATCH * NHEAD * SEQ * HDIM;  // 3,145,728 floats
    float* qf   = (float*)d_ws;
    float* kf   = qf + TEN;
    float* vf   = kf + TEN;
    float* vpre = vf + TEN;   // total 48 MB of ws

    proj_mfma_kernel<<<dim3(MTOT / 128, NHEAD, 3), 256, 0, stream>>>(
        X, Wq, bq, Wk, bk, Wv, bv, qf, kf, vf);
    vprefix_kernel<<<dim3(BATCH * NHEAD), 256, 0, stream>>>(vf, vpre);
    attn_kernel<<<dim3((SEQ / 64) * BATCH * NHEAD), 512, 0, stream>>>(
        qf, kf, vf, vpre, out);
}

// Round 4
// 259.569 us; speedup vs baseline: 2.8516x; 2.2997x over previous
//
#include <hip/hip_runtime.h>
#include <hip/hip_bf16.h>
#include <cstdint>

// Problem constants (LongformerSelfAttention: B=2, S=2048, M=768, H=12, D=64, W=256, DIL=1)
#define SEQ    2048
#define HIDDEN 768
#define NHEAD  12
#define HDIM   64
#define WIN    256
#define BATCH  2
#define MTOT   (BATCH * SEQ)   // 4096 tokens

typedef __attribute__((ext_vector_type(8))) short short8;   // 8 bf16 = 4 VGPR (MFMA A/B frag)
typedef __attribute__((ext_vector_type(4))) float f32x4;    // MFMA C/D frag

__device__ __forceinline__ ushort bf16_rne(float f) {
    uint u = __float_as_uint(f);
    uint r = u + 0x7FFFu + ((u >> 16) & 1u);   // round-to-nearest-even
    return (ushort)(r >> 16);
}
__device__ __forceinline__ float bf16_to_f(ushort h) {
    return __uint_as_float(((uint)h) << 16);
}

// ---------------------------------------------------------------------------
// Projection GEMM via split-bf16 MFMA (unchanged from round 3 — proven).
// ---------------------------------------------------------------------------
__global__ __launch_bounds__(256) void proj_mfma_kernel(
    const float* __restrict__ X,
    const float* __restrict__ Wq, const float* __restrict__ bq,
    const float* __restrict__ Wk, const float* __restrict__ bk,
    const float* __restrict__ Wv, const float* __restrict__ bv,
    float* __restrict__ Qo, float* __restrict__ Ko, float* __restrict__ Vo)
{
    const int which = blockIdx.z;
    const float* __restrict__ W    = (which == 0) ? Wq : (which == 1) ? Wk : Wv;
    const float* __restrict__ bias = (which == 0) ? bq : (which == 1) ? bk : bv;
    float* __restrict__ out        = (which == 0) ? Qo : (which == 1) ? Ko : Vo;
    const float scale = (which == 0) ? 0.125f : 1.0f;

    __shared__ __align__(16) ushort Ahi[128 * 64];
    __shared__ __align__(16) ushort Alo[128 * 64];
    __shared__ __align__(16) ushort Bhi[64 * 64];
    __shared__ __align__(16) ushort Blo[64 * 64];

    const int t  = threadIdx.x;
    const int m0 = blockIdx.x * 128;
    const int h  = blockIdx.y;
    const int n0 = h * 64;

    const int w    = t >> 6;
    const int lane = t & 63;
    const int wr   = w >> 1;
    const int wc   = w & 1;
    const int lr   = lane & 15;
    const int lk   = lane >> 4;

    f32x4 acc[4][2];
#pragma unroll
    for (int i = 0; i < 4; ++i)
#pragma unroll
        for (int j = 0; j < 2; ++j) acc[i][j] = (f32x4){0.f, 0.f, 0.f, 0.f};

    for (int k0 = 0; k0 < HIDDEN; k0 += 64) {
        __syncthreads();
#pragma unroll
        for (int i = 0; i < 8; ++i) {
            int id  = t + i * 256;
            int row = id >> 4;
            int c4  = id & 15;
            const float4 xv = *(const float4*)&X[(size_t)(m0 + row) * HIDDEN + k0 + c4 * 4];
            ushort h0 = bf16_rne(xv.x), h1 = bf16_rne(xv.y),
                   h2 = bf16_rne(xv.z), h3 = bf16_rne(xv.w);
            ushort l0 = bf16_rne(xv.x - bf16_to_f(h0)),
                   l1 = bf16_rne(xv.y - bf16_to_f(h1)),
                   l2 = bf16_rne(xv.z - bf16_to_f(h2)),
                   l3 = bf16_rne(xv.w - bf16_to_f(h3));
            int idx = (row * 64 + c4 * 4) ^ ((row & 7) << 3);
            *(uint2*)&Ahi[idx] = make_uint2((uint)h0 | ((uint)h1 << 16),
                                            (uint)h2 | ((uint)h3 << 16));
            *(uint2*)&Alo[idx] = make_uint2((uint)l0 | ((uint)l1 << 16),
                                            (uint)l2 | ((uint)l3 << 16));
        }
#pragma unroll
        for (int i = 0; i < 4; ++i) {
            int id  = t + i * 256;
            int row = id >> 4;
            int c4  = id & 15;
            const float4 wv4 = *(const float4*)&W[(size_t)(n0 + row) * HIDDEN + k0 + c4 * 4];
            ushort h0 = bf16_rne(wv4.x), h1 = bf16_rne(wv4.y),
                   h2 = bf16_rne(wv4.z), h3 = bf16_rne(wv4.w);
            ushort l0 = bf16_rne(wv4.x - bf16_to_f(h0)),
                   l1 = bf16_rne(wv4.y - bf16_to_f(h1)),
                   l2 = bf16_rne(wv4.z - bf16_to_f(h2)),
                   l3 = bf16_rne(wv4.w - bf16_to_f(h3));
            int idx = (row * 64 + c4 * 4) ^ ((row & 7) << 3);
            *(uint2*)&Bhi[idx] = make_uint2((uint)h0 | ((uint)h1 << 16),
                                            (uint)h2 | ((uint)h3 << 16));
            *(uint2*)&Blo[idx] = make_uint2((uint)l0 | ((uint)l1 << 16),
                                            (uint)l2 | ((uint)l3 << 16));
        }
        __syncthreads();

#pragma unroll
        for (int s = 0; s < 2; ++s) {
            short8 ah[4], al[4], bh[2], bl[2];
#pragma unroll
            for (int fm = 0; fm < 4; ++fm) {
                int row = wr * 64 + fm * 16 + lr;
                int idx = (row * 64 + s * 32 + lk * 8) ^ ((row & 7) << 3);
                ah[fm] = *(const short8*)&Ahi[idx];
                al[fm] = *(const short8*)&Alo[idx];
            }
#pragma unroll
            for (int fn = 0; fn < 2; ++fn) {
                int row = wc * 32 + fn * 16 + lr;
                int idx = (row * 64 + s * 32 + lk * 8) ^ ((row & 7) << 3);
                bh[fn] = *(const short8*)&Bhi[idx];
                bl[fn] = *(const short8*)&Blo[idx];
            }
#pragma unroll
            for (int fm = 0; fm < 4; ++fm)
#pragma unroll
                for (int fn = 0; fn < 2; ++fn) {
                    acc[fm][fn] = __builtin_amdgcn_mfma_f32_16x16x32_bf16(
                        ah[fm], bh[fn], acc[fm][fn], 0, 0, 0);
                    acc[fm][fn] = __builtin_amdgcn_mfma_f32_16x16x32_bf16(
                        ah[fm], bl[fn], acc[fm][fn], 0, 0, 0);
                    acc[fm][fn] = __builtin_amdgcn_mfma_f32_16x16x32_bf16(
                        al[fm], bh[fn], acc[fm][fn], 0, 0, 0);
                }
        }
    }

#pragma unroll
    for (int fn = 0; fn < 2; ++fn) {
        int d = wc * 32 + fn * 16 + lr;
        float bval = bias[n0 + d];
#pragma unroll
        for (int fm = 0; fm < 4; ++fm) {
#pragma unroll
            for (int r = 0; r < 4; ++r) {
                int m  = m0 + wr * 64 + fm * 16 + lk * 4 + r;
                int bb = m >> 11;
                int ss = m & (SEQ - 1);
                out[(((size_t)(bb * NHEAD + h) * SEQ) + ss) * HDIM + d] =
                    (acc[fm][fn][r] + bval) * scale;
            }
        }
    }
}

// ---------------------------------------------------------------------------
// Prefix sum of V along sequence per (b,h,d) (unchanged).
// ---------------------------------------------------------------------------
__global__ __launch_bounds__(256) void vprefix_kernel(
    const float* __restrict__ V, float* __restrict__ Vpre)
{
    const int bh    = blockIdx.x;
    const int d     = threadIdx.x & 63;
    const int chunk = threadIdx.x >> 6;
    const float* vb = &V[(size_t)bh * SEQ * HDIM];
    float* pb       = &Vpre[(size_t)bh * SEQ * HDIM];

    __shared__ float csum[4][64];
    const int s0 = chunk * 512;
    float sum = 0.f;
    for (int s = s0; s < s0 + 512; ++s) sum += vb[(size_t)s * HDIM + d];
    csum[chunk][d] = sum;
    __syncthreads();
    float run = 0.f;
    for (int c = 0; c < chunk; ++c) run += csum[c][d];
    for (int s = s0; s < s0 + 512; ++s) {
        run += vb[(size_t)s * HDIM + d];
        pb[(size_t)s * HDIM + d] = run;
    }
}

// ---------------------------------------------------------------------------
// Banded attention v3 — split-bf16 MFMA, both GEMMs operand-swapped.
//   S^T  = K · Q^T    (A = K rows from swizzled LDS, B = Q rows in registers)
//   ctx^T = V^T · P^T (A = V^T staged transposed,    B = P rows via LDS)
// Lane's column (lane&15) = its q-row for BOTH accs -> softmax state and
// rescale stay lane-local; row-reduce = 16 in-reg values + shfl_xor(16,32).
// Split hi/lo (drop lo*lo) keeps fp32-class precision on both GEMMs.
// Block = 64 q x one (b,h), 4 waves (16 q each); 9 K/V tiles of 64.
// LDS 48 KB -> exactly 3 blocks/CU on the 768-block grid.
// Multiplicative mask faithful: mrun init 0; out-of-window correction via
// Vpre prefix sums in the epilogue (exact).
// ---------------------------------------------------------------------------
__global__ __launch_bounds__(256, 3) void attn_kernel(
    const float* __restrict__ Q, const float* __restrict__ K,
    const float* __restrict__ V, const float* __restrict__ Vpre,
    float* __restrict__ out)
{
    __shared__ __align__(16) ushort Khi[64 * 64], Klo[64 * 64];   // [key][d] ^((key&7)<<3)
    __shared__ __align__(16) ushort VThi[64 * 64], VTlo[64 * 64]; // [d][key] ^((d&7)<<3)
    __shared__ __align__(16) ushort Phi_s[4][16 * 64];            // per-wave [q][key] ^((q&7)<<3)
    __shared__ __align__(16) ushort Plo_s[4][16 * 64];

    const int t    = threadIdx.x;
    const int lane = t & 63;
    const int wv   = t >> 6;                   // wave 0..3 -> q rows wv*16..+15
    const int l15  = lane & 15;
    const int g2   = lane >> 4;                // 0..3

    const int L    = blockIdx.x;
    const int xcd  = L & 7;
    const int slot = L >> 3;                   // 0..95
    const int bh   = xcd * 3 + (slot >> 5);
    const int qb   = slot & 31;
    const int b    = bh / NHEAD;
    const int h    = bh % NHEAD;
    const int i0   = qb * 64;
    const int i    = i0 + wv * 16 + l15;       // this lane's q row (acc column)

    const float* kbase = &K[(size_t)bh * SEQ * HDIM];
    const float* vbase = &V[(size_t)bh * SEQ * HDIM];

    // ---- Q fragments (B-operand), hoisted: k-step s needs q-row d-slice
    //      s*32 + g2*8 .. +8, as bf16 hi/lo ----
    short8 qh[2], qlo[2];
    {
        const float* qrow = &Q[((size_t)bh * SEQ + i) * HDIM];
#pragma unroll
        for (int s = 0; s < 2; ++s) {
            float4 a = *(const float4*)&qrow[s * 32 + g2 * 8];
            float4 c = *(const float4*)&qrow[s * 32 + g2 * 8 + 4];
            float qf[8] = {a.x, a.y, a.z, a.w, c.x, c.y, c.z, c.w};
#pragma unroll
            for (int j = 0; j < 8; ++j) {
                ushort hh = bf16_rne(qf[j]);
                qh[s][j]  = (short)hh;
                qlo[s][j] = (short)bf16_rne(qf[j] - bf16_to_f(hh));
            }
        }
    }

    // ---- staging assignment (whole block stages shared K / V^T) ----
    const int krow = t >> 2;                   // 0..63 (key row)
    const int kc   = (t & 3) * 16;             // d offset, 16 floats
    const int vkp  = t >> 3;                   // 0..31 -> keys 2vkp, 2vkp+1
    const int vdc  = (t & 7) * 8;              // d offset, 8 floats
    float4 kpre[4], vp0[2], vp1[2];

    const int jlo_blk = max(0, i0 - WIN);
    const int jhi_blk = min(SEQ - 1, i0 + 63 + WIN);

    auto LOADT = [&](int jt2) {
        const float* kr = &kbase[(size_t)(jt2 + krow) * HDIM + kc];
        kpre[0] = *(const float4*)&kr[0];
        kpre[1] = *(const float4*)&kr[4];
        kpre[2] = *(const float4*)&kr[8];
        kpre[3] = *(const float4*)&kr[12];
        const float* vr0 = &vbase[(size_t)(jt2 + 2 * vkp) * HDIM + vdc];
        const float* vr1 = &vbase[(size_t)(jt2 + 2 * vkp + 1) * HDIM + vdc];
        vp0[0] = *(const float4*)&vr0[0];
        vp0[1] = *(const float4*)&vr0[4];
        vp1[0] = *(const float4*)&vr1[0];
        vp1[1] = *(const float4*)&vr1[4];
    };
    auto STORET = [&]() {
        // K tile: 16 floats -> hi/lo bf16, 4+4 uint2 writes
#pragma unroll
        for (int c = 0; c < 4; ++c) {
            float x0 = kpre[c].x, x1 = kpre[c].y, x2 = kpre[c].z, x3 = kpre[c].w;
            ushort h0 = bf16_rne(x0), h1 = bf16_rne(x1),
                   h2 = bf16_rne(x2), h3 = bf16_rne(x3);
            ushort l0 = bf16_rne(x0 - bf16_to_f(h0)),
                   l1 = bf16_rne(x1 - bf16_to_f(h1)),
                   l2 = bf16_rne(x2 - bf16_to_f(h2)),
                   l3 = bf16_rne(x3 - bf16_to_f(h3));
            int idx = (krow * 64 + kc + c * 4) ^ ((krow & 7) << 3);
            *(uint2*)&Khi[idx] = make_uint2((uint)h0 | ((uint)h1 << 16),
                                            (uint)h2 | ((uint)h3 << 16));
            *(uint2*)&Klo[idx] = make_uint2((uint)l0 | ((uint)l1 << 16),
                                            (uint)l2 | ((uint)l3 << 16));
        }
        // V^T tile: transpose on write, pairs of keys packed per b32
        float va[8] = {vp0[0].x, vp0[0].y, vp0[0].z, vp0[0].w,
                       vp0[1].x, vp0[1].y, vp0[1].z, vp0[1].w};
        float vb8[8] = {vp1[0].x, vp1[0].y, vp1[0].z, vp1[0].w,
                        vp1[1].x, vp1[1].y, vp1[1].z, vp1[1].w};
#pragma unroll
        for (int j = 0; j < 8; ++j) {
            int d = vdc + j;
            ushort ah = bf16_rne(va[j]), bh2 = bf16_rne(vb8[j]);
            ushort al = bf16_rne(va[j] - bf16_to_f(ah)),
                   bl = bf16_rne(vb8[j] - bf16_to_f(bh2));
            int idx = (d * 64 + 2 * vkp) ^ ((d & 7) << 3);
            *(uint*)&VThi[idx] = (uint)ah | ((uint)bh2 << 16);
            *(uint*)&VTlo[idx] = (uint)al | ((uint)bl << 16);
        }
    };

    float mrun = 0.f, lrun = 0.f;              // mask zeros always in softmax set
    f32x4 ctx[4];
#pragma unroll
    for (int f = 0; f < 4; ++f) ctx[f] = (f32x4){0.f, 0.f, 0.f, 0.f};

    LOADT(jlo_blk);
    STORET();                                   // preload tile 0

    for (int jt = jlo_blk; jt <= jhi_blk; jt += 64) {
        const bool more = (jt + 64) <= jhi_blk;
        if (more) LOADT(jt + 64);               // T14: issue early, write late
        __syncthreads();                        // staged tile visible

        // ---- QK^T: S^T[64 keys][16 q] ----
        f32x4 sacc[4];
#pragma unroll
        for (int f = 0; f < 4; ++f) sacc[f] = (f32x4){0.f, 0.f, 0.f, 0.f};
#pragma unroll
        for (int s = 0; s < 2; ++s) {
            short8 kh[4], kl[4];
#pragma unroll
            for (int f = 0; f < 4; ++f) {
                int row = f * 16 + l15;
                int idx = (row * 64 + s * 32 + g2 * 8) ^ ((row & 7) << 3);
                kh[f] = *(const short8*)&Khi[idx];
                kl[f] = *(const short8*)&Klo[idx];
            }
#pragma unroll
            for (int f = 0; f < 4; ++f) {
                sacc[f] = __builtin_amdgcn_mfma_f32_16x16x32_bf16(kh[f], qh[s],  sacc[f], 0, 0, 0);
                sacc[f] = __builtin_amdgcn_mfma_f32_16x16x32_bf16(kh[f], qlo[s], sacc[f], 0, 0, 0);
                sacc[f] = __builtin_amdgcn_mfma_f32_16x16x32_bf16(kl[f], qh[s],  sacc[f], 0, 0, 0);
            }
        }

        // ---- softmax (lane-local rows; key j = jt + f*16 + g2*4 + r) ----
        float p[4][4];
        float tmax = -1e30f;
#pragma unroll
        for (int f = 0; f < 4; ++f)
#pragma unroll
            for (int r = 0; r < 4; ++r) {
                int j = jt + f * 16 + g2 * 4 + r;
                bool inw = (j >= i - WIN) && (j <= i + WIN);
                float sv_ = inw ? sacc[f][r] : -1e30f;
                p[f][r] = sv_;
                tmax = fmaxf(tmax, sv_);
            }
        tmax = fmaxf(tmax, __shfl_xor(tmax, 16));
        tmax = fmaxf(tmax, __shfl_xor(tmax, 32));
        float m_new = fmaxf(mrun, tmax);
        float resc  = __expf(mrun - m_new);
        float lsum  = 0.f;
#pragma unroll
        for (int f = 0; f < 4; ++f)
#pragma unroll
            for (int r = 0; r < 4; ++r) {
                float pe = __expf(p[f][r] - m_new);
                p[f][r] = pe;
                lsum += pe;
            }
        lsum += __shfl_xor(lsum, 16);
        lsum += __shfl_xor(lsum, 32);
        lrun = lrun * resc + lsum;
        mrun = m_new;
#pragma unroll
        for (int f = 0; f < 4; ++f) {
            ctx[f][0] *= resc; ctx[f][1] *= resc;
            ctx[f][2] *= resc; ctx[f][3] *= resc;
        }

        // ---- P -> bf16 hi/lo into per-wave LDS ([q][key], swizzled) ----
#pragma unroll
        for (int f = 0; f < 4; ++f) {
            ushort h0 = bf16_rne(p[f][0]), h1 = bf16_rne(p[f][1]),
                   h2 = bf16_rne(p[f][2]), h3 = bf16_rne(p[f][3]);
            ushort l0 = bf16_rne(p[f][0] - bf16_to_f(h0)),
                   l1 = bf16_rne(p[f][1] - bf16_to_f(h1)),
                   l2 = bf16_rne(p[f][2] - bf16_to_f(h2)),
                   l3 = bf16_rne(p[f][3] - bf16_to_f(h3));
            int idx = (l15 * 64 + f * 16 + g2 * 4) ^ ((l15 & 7) << 3);
            *(uint2*)&Phi_s[wv][idx] = make_uint2((uint)h0 | ((uint)h1 << 16),
                                                  (uint)h2 | ((uint)h3 << 16));
            *(uint2*)&Plo_s[wv][idx] = make_uint2((uint)l0 | ((uint)l1 << 16),
                                                  (uint)l2 | ((uint)l3 << 16));
        }

        // ---- PV: ctx^T[64 d][16 q] += V^T · P^T ----
#pragma unroll
        for (int s = 0; s < 2; ++s) {
            int pidx = (l15 * 64 + s * 32 + g2 * 8) ^ ((l15 & 7) << 3);
            short8 ph = *(const short8*)&Phi_s[wv][pidx];
            short8 pl = *(const short8*)&Plo_s[wv][pidx];
#pragma unroll
            for (int f = 0; f < 4; ++f) {
                int row = f * 16 + l15;
                int idx = (row * 64 + s * 32 + g2 * 8) ^ ((row & 7) << 3);
                short8 vh = *(const short8*)&VThi[idx];
                short8 vl = *(const short8*)&VTlo[idx];
                ctx[f] = __builtin_amdgcn_mfma_f32_16x16x32_bf16(vh, ph, ctx[f], 0, 0, 0);
                ctx[f] = __builtin_amdgcn_mfma_f32_16x16x32_bf16(vl, ph, ctx[f], 0, 0, 0);
                ctx[f] = __builtin_amdgcn_mfma_f32_16x16x32_bf16(vh, pl, ctx[f], 0, 0, 0);
            }
        }

        __syncthreads();                        // all reads of this tile done
        if (more) STORET();                     // commit prefetched tile
    }

    // ---- out-of-window correction + normalize + store (ctx^T layout:
    //      lane holds q = l15's column, d = f*16 + g2*4 + {0..3}) ----
    const int jlo = max(0, i - WIN);
    const int jhi = min(SEQ - 1, i + WIN);
    const int cnt = jhi - jlo + 1;
    const float em   = __expf(-mrun);
    const float ltot = lrun + (float)(SEQ - cnt) * em;
    const float inv  = 1.f / ltot;

    const float* vpT = &Vpre[((size_t)bh * SEQ + (SEQ - 1)) * HDIM];
    const float* vpH = &Vpre[((size_t)bh * SEQ + jhi) * HDIM];
    const float* vpL = &Vpre[((size_t)bh * SEQ + (jlo - 1)) * HDIM];  // read only if jlo>0
    float* orow = &out[((size_t)(b * SEQ + i)) * HIDDEN + h * HDIM];

#pragma unroll
    for (int f = 0; f < 4; ++f) {
        int d0 = f * 16 + g2 * 4;
        float4 tt = *(const float4*)&vpT[d0];
        float4 hh = *(const float4*)&vpH[d0];
        float4 ll = {0.f, 0.f, 0.f, 0.f};
        if (jlo > 0) ll = *(const float4*)&vpL[d0];
        float4 o;
        o.x = (ctx[f][0] + em * (tt.x - hh.x + ll.x)) * inv;
        o.y = (ctx[f][1] + em * (tt.y - hh.y + ll.y)) * inv;
        o.z = (ctx[f][2] + em * (tt.z - hh.z + ll.z)) * inv;
        o.w = (ctx[f][3] + em * (tt.w - hh.w + ll.w)) * inv;
        *(float4*)&orow[d0] = o;
    }
}

// ---------------------------------------------------------------------------
extern "C" void kernel_launch(void* const* d_in, const int* in_sizes, int n_in,
                              void* d_out, int out_size, void* d_ws, size_t ws_size,
                              hipStream_t stream) {
    const float* X  = (const float*)d_in[0];
    const float* Wq = (const float*)d_in[1];
    const float* bq = (const float*)d_in[2];
    const float* Wk = (const float*)d_in[3];
    const float* bk = (const float*)d_in[4];
    const float* Wv = (const float*)d_in[5];
    const float* bv = (const float*)d_in[6];
    float* out = (float*)d_out;

    const size_t TEN = (size_t)BATCH * NHEAD * SEQ * HDIM;  // 3,145,728 floats
    float* qf   = (float*)d_ws;
    float* kf   = qf + TEN;
    float* vf   = kf + TEN;
    float* vpre = vf + TEN;   // 48 MB of ws

    proj_mfma_kernel<<<dim3(MTOT / 128, NHEAD, 3), 256, 0, stream>>>(
        X, Wq, bq, Wk, bk, Wv, bv, qf, kf, vf);
    vprefix_kernel<<<dim3(BATCH * NHEAD), 256, 0, stream>>>(vf, vpre);
    attn_kernel<<<dim3((SEQ / 64) * BATCH * NHEAD), 256, 0, stream>>>(
        qf, kf, vf, vpre, out);
}